// Round 1
// baseline (1238.509 us; speedup 1.0000x reference)
//
#include <hip/hip_runtime.h>
#include <math.h>

#define NN 40000
#define NE 640000
#define CDIM 128
#define HEADS 8
#define DHEAD 16
#define OUTDIM 64

__device__ __forceinline__ float gelu_tanh(float x) {
    float x3 = x * x * x;
    float u = 0.7978845608028654f * (x + 0.044715f * x3);
    return 0.5f * x * (1.0f + tanhf(u));
}

// Build fused QKV weight matrix Bf[128][384] and bias[384]:
//   cols   0..127 : Wq (copy), bias bq
//   cols 128..255 : Wk @ blockdiag(a_rel) scaled by p_rel[h]*0.25  (logit scale folded in)
//   cols 256..383 : Wv @ blockdiag(m_rel)
__global__ __launch_bounds__(256) void fuse_kernel(
    const float* __restrict__ Wq, const float* __restrict__ bq,
    const float* __restrict__ Wk, const float* __restrict__ bk,
    const float* __restrict__ a_rel,
    const float* __restrict__ Wv, const float* __restrict__ bv,
    const float* __restrict__ m_rel,
    const float* __restrict__ p_rel,
    float* __restrict__ Bf, float* __restrict__ biasf)
{
    int idx = blockIdx.x * 256 + threadIdx.x;
    if (idx >= 129 * 384) return;
    int r = idx / 384;          // 0..127 = weight row, 128 = bias row
    int col = idx - r * 384;
    float val;
    if (col < 128) {
        val = (r < 128) ? Wq[r * 128 + col] : bq[col];
    } else if (col < 256) {
        int cc = col - 128; int h = cc >> 4; int eo = cc & 15;
        float scale = p_rel[h] * 0.25f;   // p_rel * 1/sqrt(16)
        float s = 0.f;
        #pragma unroll
        for (int d = 0; d < 16; ++d) {
            float w = (r < 128) ? Wk[r * 128 + h * 16 + d] : bk[h * 16 + d];
            s += w * a_rel[h * 256 + d * 16 + eo];
        }
        val = s * scale;
    } else {
        int cc = col - 256; int h = cc >> 4; int eo = cc & 15;
        float s = 0.f;
        #pragma unroll
        for (int d = 0; d < 16; ++d) {
            float w = (r < 128) ? Wv[r * 128 + h * 16 + d] : bv[h * 16 + d];
            s += w * m_rel[h * 256 + d * 16 + eo];
        }
        val = s;
    }
    if (r < 128) Bf[r * 384 + col] = val;
    else         biasf[col] = val;
}

// Tiled f32 GEMM: C = f(A) * B + bias, A:[M x 128], B:[128 x Nld], tile 64x64, BK=64.
// MODE 0: plain (QKV).  MODE 1: gelu on A, epilogue h = relu(beta*(.) + (1-beta)*Hprev).
// MODE 2: plain (final fc).
template <int MODE>
__global__ __launch_bounds__(256) void gemm_kernel(
    const float* __restrict__ A, const float* __restrict__ B,
    const float* __restrict__ bias, float* __restrict__ Cout,
    const float* __restrict__ Hprev, const float* __restrict__ skip_p,
    int Nld)
{
    __shared__ float As[64][68];
    __shared__ float Bs[64][64];
    int t = threadIdx.x;
    int row0 = blockIdx.x * 64;
    int col0 = blockIdx.y * 64;
    int ty = t >> 4, tx = t & 15;
    float acc[4][4] = {};

    for (int kb = 0; kb < 128; kb += 64) {
        #pragma unroll
        for (int i = 0; i < 4; ++i) {
            int idx = t + i * 256;
            int r = idx >> 4;
            int c4 = (idx & 15) << 2;
            float4 v = *(const float4*)(A + (size_t)(row0 + r) * 128 + kb + c4);
            if (MODE == 1) {
                v.x = gelu_tanh(v.x); v.y = gelu_tanh(v.y);
                v.z = gelu_tanh(v.z); v.w = gelu_tanh(v.w);
            }
            *(float4*)(&As[r][c4]) = v;
        }
        #pragma unroll
        for (int i = 0; i < 4; ++i) {
            int idx = t + i * 256;
            int r = idx >> 4;
            int c4 = (idx & 15) << 2;
            float4 v = *(const float4*)(B + (size_t)(kb + r) * Nld + col0 + c4);
            *(float4*)(&Bs[r][c4]) = v;
        }
        __syncthreads();
        #pragma unroll
        for (int k = 0; k < 64; k += 4) {
            float af[4][4], bf[4][4];
            *(float4*)&af[0][0] = *(const float4*)(&As[ty * 4 + 0][k]);
            *(float4*)&af[1][0] = *(const float4*)(&As[ty * 4 + 1][k]);
            *(float4*)&af[2][0] = *(const float4*)(&As[ty * 4 + 2][k]);
            *(float4*)&af[3][0] = *(const float4*)(&As[ty * 4 + 3][k]);
            *(float4*)&bf[0][0] = *(const float4*)(&Bs[k + 0][tx * 4]);
            *(float4*)&bf[1][0] = *(const float4*)(&Bs[k + 1][tx * 4]);
            *(float4*)&bf[2][0] = *(const float4*)(&Bs[k + 2][tx * 4]);
            *(float4*)&bf[3][0] = *(const float4*)(&Bs[k + 3][tx * 4]);
            #pragma unroll
            for (int kk = 0; kk < 4; ++kk)
                #pragma unroll
                for (int i = 0; i < 4; ++i)
                    #pragma unroll
                    for (int j = 0; j < 4; ++j)
                        acc[i][j] += af[i][kk] * bf[kk][j];
        }
        __syncthreads();
    }

    float beta = 0.f, omb = 0.f;
    if (MODE == 1) {
        float sv = skip_p[0];
        beta = 1.f / (1.f + expf(-sv));
        omb = 1.f - beta;
    }
    #pragma unroll
    for (int i = 0; i < 4; ++i) {
        int row = row0 + ty * 4 + i;
        int colb = col0 + tx * 4;
        float4 vv;
        vv.x = acc[i][0] + bias[colb + 0];
        vv.y = acc[i][1] + bias[colb + 1];
        vv.z = acc[i][2] + bias[colb + 2];
        vv.w = acc[i][3] + bias[colb + 3];
        if (MODE == 1) {
            float4 hp = *(const float4*)(Hprev + (size_t)row * 128 + colb);
            vv.x = fmaxf(beta * vv.x + omb * hp.x, 0.f);
            vv.y = fmaxf(beta * vv.y + omb * hp.y, 0.f);
            vv.z = fmaxf(beta * vv.z + omb * hp.z, 0.f);
            vv.w = fmaxf(beta * vv.w + omb * hp.w, 0.f);
        }
        *(float4*)(Cout + (size_t)row * Nld + colb) = vv;
    }
}

// Per-edge attention logits -> exp -> atomic denominator.
// qkv layout per node row (stride 384): [q(128) | k2_scaled(128) | v2(128)]
__global__ __launch_bounds__(256) void logits_kernel(
    const float* __restrict__ qkv, const int* __restrict__ eidx,
    float* __restrict__ alpha, float* __restrict__ sden)
{
    int t = threadIdx.x;
    int c = t & 127;
    int e = blockIdx.x * 2 + (t >> 7);
    int srcN = eidx[e];
    int dstN = eidx[NE + e];
    float qv = qkv[(size_t)dstN * 384 + c];
    float kv = qkv[(size_t)srcN * 384 + 128 + c];
    float v = qv * kv;
    v += __shfl_xor(v, 8, 16);
    v += __shfl_xor(v, 4, 16);
    v += __shfl_xor(v, 2, 16);
    v += __shfl_xor(v, 1, 16);
    if ((c & 15) == 0) {
        int h = c >> 4;
        float ev = expf(v);          // no max-subtraction: logits are O(1)
        alpha[e * 8 + h] = ev;
        atomicAdd(&sden[dstN * 8 + h], ev);
    }
}

// Normalize and scatter messages: agg[dst, c] += v2[src, c] * alpha_norm
__global__ __launch_bounds__(256) void msg_kernel(
    const float* __restrict__ qkv, const int* __restrict__ eidx,
    const float* __restrict__ alpha, const float* __restrict__ sden,
    float* __restrict__ agg)
{
    int t = threadIdx.x;
    int c = t & 127;
    int e = blockIdx.x * 2 + (t >> 7);
    int srcN = eidx[e];
    int dstN = eidx[NE + e];
    int h = c >> 4;
    float w = alpha[e * 8 + h] / (sden[dstN * 8 + h] + 1e-16f);
    float vv = qkv[(size_t)srcN * 384 + 256 + c];
    atomicAdd(&agg[(size_t)dstN * 128 + c], vv * w);
}

extern "C" void kernel_launch(void* const* d_in, const int* in_sizes, int n_in,
                              void* d_out, int out_size, void* d_ws, size_t ws_size,
                              hipStream_t stream) {
    const float* x     = (const float*)d_in[0];
    const int*   eidx  = (const int*)d_in[1];
    const float* Wk    = (const float*)d_in[2];
    const float* bk    = (const float*)d_in[3];
    const float* Wq    = (const float*)d_in[4];
    const float* bq    = (const float*)d_in[5];
    const float* Wv    = (const float*)d_in[6];
    const float* bv    = (const float*)d_in[7];
    const float* a_rel = (const float*)d_in[8];
    const float* m_rel = (const float*)d_in[9];
    const float* p_rel = (const float*)d_in[10];
    const float* skip  = (const float*)d_in[11];
    const float* aW    = (const float*)d_in[12];
    const float* ab    = (const float*)d_in[13];
    const float* fcW   = (const float*)d_in[14];
    const float* fcb   = (const float*)d_in[15];
    float* out = (float*)d_out;

    float* ws    = (float*)d_ws;
    float* h     = ws;                         // NN*128
    float* qkv   = h + (size_t)NN * 128;       // NN*384
    float* alpha = qkv + (size_t)NN * 384;     // NE*8
    float* sden  = alpha + (size_t)NE * 8;     // NN*8
    float* agg   = sden + (size_t)NN * 8;      // NN*128
    float* Bf    = agg + (size_t)NN * 128;     // 128*384
    float* biasf = Bf + 128 * 384;             // 384

    for (int l = 0; l < 2; ++l) {
        const float* hc = (l == 0) ? x : h;
        fuse_kernel<<<194, 256, 0, stream>>>(
            Wq + l * 16384, bq + l * 128,
            Wk + l * 16384, bk + l * 128, a_rel + l * 2048,
            Wv + l * 16384, bv + l * 128, m_rel + l * 2048,
            p_rel + l * 8, Bf, biasf);
        gemm_kernel<0><<<dim3(625, 6), 256, 0, stream>>>(
            hc, Bf, biasf, qkv, nullptr, nullptr, 384);
        hipMemsetAsync(sden, 0, (size_t)NN * 8 * sizeof(float), stream);
        hipMemsetAsync(agg, 0, (size_t)NN * 128 * sizeof(float), stream);
        logits_kernel<<<NE / 2, 256, 0, stream>>>(qkv, eidx, alpha, sden);
        msg_kernel<<<NE / 2, 256, 0, stream>>>(qkv, eidx, alpha, sden, agg);
        gemm_kernel<1><<<dim3(625, 2), 256, 0, stream>>>(
            agg, aW + l * 16384, ab + l * 128, h, hc, skip + l, 128);
    }
    gemm_kernel<2><<<dim3(625, 1), 256, 0, stream>>>(
        h, fcW, fcb, out, nullptr, nullptr, 64);
}

// Round 2
// 551.489 us; speedup vs baseline: 2.2458x; 2.2458x over previous
//
#include <hip/hip_runtime.h>
#include <math.h>

#define NN 40000
#define NE 640000
#define CDIM 128
#define HEADS 8
#define DHEAD 16
#define OUTDIM 64
#define NB_SCAN 157   // ceil(NN/256)

__device__ __forceinline__ float gelu_tanh(float x) {
    float x3 = x * x * x;
    float u = 0.7978845608028654f * (x + 0.044715f * x3);
    return 0.5f * x * (1.0f + tanhf(u));
}

// Build fused QKV weight matrix Bf[128][384] and bias[384]:
//   cols   0..127 : Wq (copy), bias bq
//   cols 128..255 : Wk @ blockdiag(a_rel) scaled by p_rel[h]*0.25  (logit scale folded in)
//   cols 256..383 : Wv @ blockdiag(m_rel)
__global__ __launch_bounds__(256) void fuse_kernel(
    const float* __restrict__ Wq, const float* __restrict__ bq,
    const float* __restrict__ Wk, const float* __restrict__ bk,
    const float* __restrict__ a_rel,
    const float* __restrict__ Wv, const float* __restrict__ bv,
    const float* __restrict__ m_rel,
    const float* __restrict__ p_rel,
    float* __restrict__ Bf, float* __restrict__ biasf)
{
    int idx = blockIdx.x * 256 + threadIdx.x;
    if (idx >= 129 * 384) return;
    int r = idx / 384;          // 0..127 = weight row, 128 = bias row
    int col = idx - r * 384;
    float val;
    if (col < 128) {
        val = (r < 128) ? Wq[r * 128 + col] : bq[col];
    } else if (col < 256) {
        int cc = col - 128; int h = cc >> 4; int eo = cc & 15;
        float scale = p_rel[h] * 0.25f;   // p_rel * 1/sqrt(16)
        float s = 0.f;
        #pragma unroll
        for (int d = 0; d < 16; ++d) {
            float w = (r < 128) ? Wk[r * 128 + h * 16 + d] : bk[h * 16 + d];
            s += w * a_rel[h * 256 + d * 16 + eo];
        }
        val = s * scale;
    } else {
        int cc = col - 256; int h = cc >> 4; int eo = cc & 15;
        float s = 0.f;
        #pragma unroll
        for (int d = 0; d < 16; ++d) {
            float w = (r < 128) ? Wv[r * 128 + h * 16 + d] : bv[h * 16 + d];
            s += w * m_rel[h * 256 + d * 16 + eo];
        }
        val = s;
    }
    if (r < 128) Bf[r * 384 + col] = val;
    else         biasf[col] = val;
}

// Tiled f32 GEMM: C = f(A) * B + bias, A:[M x 128], B:[128 x Nld], tile 64x64, BK=64.
// MODE 0: plain (QKV).  MODE 1: gelu on A, epilogue h = relu(beta*(.) + (1-beta)*Hprev).
// MODE 2: plain (final fc).
template <int MODE>
__global__ __launch_bounds__(256) void gemm_kernel(
    const float* __restrict__ A, const float* __restrict__ B,
    const float* __restrict__ bias, float* __restrict__ Cout,
    const float* __restrict__ Hprev, const float* __restrict__ skip_p,
    int Nld)
{
    __shared__ float As[64][68];
    __shared__ float Bs[64][64];
    int t = threadIdx.x;
    int row0 = blockIdx.x * 64;
    int col0 = blockIdx.y * 64;
    int ty = t >> 4, tx = t & 15;
    float acc[4][4] = {};

    for (int kb = 0; kb < 128; kb += 64) {
        #pragma unroll
        for (int i = 0; i < 4; ++i) {
            int idx = t + i * 256;
            int r = idx >> 4;
            int c4 = (idx & 15) << 2;
            float4 v = *(const float4*)(A + (size_t)(row0 + r) * 128 + kb + c4);
            if (MODE == 1) {
                v.x = gelu_tanh(v.x); v.y = gelu_tanh(v.y);
                v.z = gelu_tanh(v.z); v.w = gelu_tanh(v.w);
            }
            *(float4*)(&As[r][c4]) = v;
        }
        #pragma unroll
        for (int i = 0; i < 4; ++i) {
            int idx = t + i * 256;
            int r = idx >> 4;
            int c4 = (idx & 15) << 2;
            float4 v = *(const float4*)(B + (size_t)(kb + r) * Nld + col0 + c4);
            *(float4*)(&Bs[r][c4]) = v;
        }
        __syncthreads();
        #pragma unroll
        for (int k = 0; k < 64; k += 4) {
            float af[4][4], bf[4][4];
            *(float4*)&af[0][0] = *(const float4*)(&As[ty * 4 + 0][k]);
            *(float4*)&af[1][0] = *(const float4*)(&As[ty * 4 + 1][k]);
            *(float4*)&af[2][0] = *(const float4*)(&As[ty * 4 + 2][k]);
            *(float4*)&af[3][0] = *(const float4*)(&As[ty * 4 + 3][k]);
            *(float4*)&bf[0][0] = *(const float4*)(&Bs[k + 0][tx * 4]);
            *(float4*)&bf[1][0] = *(const float4*)(&Bs[k + 1][tx * 4]);
            *(float4*)&bf[2][0] = *(const float4*)(&Bs[k + 2][tx * 4]);
            *(float4*)&bf[3][0] = *(const float4*)(&Bs[k + 3][tx * 4]);
            #pragma unroll
            for (int kk = 0; kk < 4; ++kk)
                #pragma unroll
                for (int i = 0; i < 4; ++i)
                    #pragma unroll
                    for (int j = 0; j < 4; ++j)
                        acc[i][j] += af[i][kk] * bf[kk][j];
        }
        __syncthreads();
    }

    float beta = 0.f, omb = 0.f;
    if (MODE == 1) {
        float sv = skip_p[0];
        beta = 1.f / (1.f + expf(-sv));
        omb = 1.f - beta;
    }
    #pragma unroll
    for (int i = 0; i < 4; ++i) {
        int row = row0 + ty * 4 + i;
        int colb = col0 + tx * 4;
        float4 vv;
        vv.x = acc[i][0] + bias[colb + 0];
        vv.y = acc[i][1] + bias[colb + 1];
        vv.z = acc[i][2] + bias[colb + 2];
        vv.w = acc[i][3] + bias[colb + 3];
        if (MODE == 1) {
            float4 hp = *(const float4*)(Hprev + (size_t)row * 128 + colb);
            vv.x = fmaxf(beta * vv.x + omb * hp.x, 0.f);
            vv.y = fmaxf(beta * vv.y + omb * hp.y, 0.f);
            vv.z = fmaxf(beta * vv.z + omb * hp.z, 0.f);
            vv.w = fmaxf(beta * vv.w + omb * hp.w, 0.f);
        }
        *(float4*)(Cout + (size_t)row * Nld + colb) = vv;
    }
}

// ---------------- CSR build (once per call; both layers share structure) ---------

__global__ __launch_bounds__(256) void hist_kernel(
    const int* __restrict__ eidx, int* __restrict__ deg)
{
    int e = blockIdx.x * 256 + threadIdx.x;
    if (e < NE) atomicAdd(&deg[eidx[NE + e]], 1);
}

__global__ __launch_bounds__(256) void scan_blocks_kernel(
    const int* __restrict__ deg, int* __restrict__ offs, int* __restrict__ bsum)
{
    __shared__ int s[256];
    int t = threadIdx.x;
    int i = blockIdx.x * 256 + t;
    int v = (i < NN) ? deg[i] : 0;
    s[t] = v;
    __syncthreads();
    #pragma unroll
    for (int off = 1; off < 256; off <<= 1) {
        int u = (t >= off) ? s[t - off] : 0;
        __syncthreads();
        s[t] += u;
        __syncthreads();
    }
    if (i < NN) offs[i] = s[t] - v;      // exclusive within block
    if (t == 255) bsum[blockIdx.x] = s[255];
}

__global__ __launch_bounds__(256) void scan_top_kernel(
    const int* __restrict__ bsum, int* __restrict__ boffs)
{
    __shared__ int s[256];
    int t = threadIdx.x;
    int v = (t < NB_SCAN) ? bsum[t] : 0;
    s[t] = v;
    __syncthreads();
    #pragma unroll
    for (int off = 1; off < 256; off <<= 1) {
        int u = (t >= off) ? s[t - off] : 0;
        __syncthreads();
        s[t] += u;
        __syncthreads();
    }
    boffs[t] = s[t] - v;                 // exclusive
}

__global__ __launch_bounds__(256) void scan_add_kernel(
    int* __restrict__ offs, const int* __restrict__ boffs, int* __restrict__ cursor)
{
    int i = blockIdx.x * 256 + threadIdx.x;
    if (i < NN) {
        int o = offs[i] + boffs[blockIdx.x];
        offs[i] = o;
        cursor[i] = o;
    }
}

__global__ __launch_bounds__(256) void scatter_kernel(
    const int* __restrict__ eidx, int* __restrict__ cursor, int* __restrict__ srcSorted)
{
    int e = blockIdx.x * 256 + threadIdx.x;
    if (e < NE) {
        int s = eidx[e];
        int d = eidx[NE + e];
        int pos = atomicAdd(&cursor[d], 1);
        srcSorted[pos] = s;
    }
}

// ---------------- Fused per-destination softmax + aggregation --------------------
// One 64-lane wave per destination node; lane handles channels 2*lane, 2*lane+1.
// Head h = lane>>3 (8 lanes per head). No atomics, agg written exactly once.
__global__ __launch_bounds__(256) void aggregate_kernel(
    const float* __restrict__ qkv, const int* __restrict__ deg,
    const int* __restrict__ offs, const int* __restrict__ srcSorted,
    float* __restrict__ agg)
{
    int wid = (blockIdx.x * 256 + threadIdx.x) >> 6;   // global wave id = node
    int lane = threadIdx.x & 63;
    int n = wid;
    float2 q2 = *(const float2*)(qkv + (size_t)n * 384 + 2 * lane);
    int start = offs[n];
    int d = deg[n];
    float accx = 0.f, accy = 0.f, den = 0.f;

    int s_cur = (d > 0) ? srcSorted[start] : 0;
    for (int j = 0; j < d; ++j) {
        int s_next = (j + 1 < d) ? srcSorted[start + j + 1] : 0;
        const float* base = qkv + (size_t)s_cur * 384 + 2 * lane;
        float2 k2 = *(const float2*)(base + 128);
        float2 v2 = *(const float2*)(base + 256);
        float p = q2.x * k2.x + q2.y * k2.y;
        p += __shfl_xor(p, 1, 8);
        p += __shfl_xor(p, 2, 8);
        p += __shfl_xor(p, 4, 8);
        float ev = expf(p);              // logits O(1): no max-subtraction needed
        den += ev;
        accx += v2.x * ev;
        accy += v2.y * ev;
        s_cur = s_next;
    }
    float w = 1.0f / (den + 1e-16f);
    float2 o;
    o.x = accx * w;
    o.y = accy * w;
    *(float2*)(agg + (size_t)n * 128 + 2 * lane) = o;
}

extern "C" void kernel_launch(void* const* d_in, const int* in_sizes, int n_in,
                              void* d_out, int out_size, void* d_ws, size_t ws_size,
                              hipStream_t stream) {
    const float* x     = (const float*)d_in[0];
    const int*   eidx  = (const int*)d_in[1];
    const float* Wk    = (const float*)d_in[2];
    const float* bk    = (const float*)d_in[3];
    const float* Wq    = (const float*)d_in[4];
    const float* bq    = (const float*)d_in[5];
    const float* Wv    = (const float*)d_in[6];
    const float* bv    = (const float*)d_in[7];
    const float* a_rel = (const float*)d_in[8];
    const float* m_rel = (const float*)d_in[9];
    const float* p_rel = (const float*)d_in[10];
    const float* skip  = (const float*)d_in[11];
    const float* aW    = (const float*)d_in[12];
    const float* ab    = (const float*)d_in[13];
    const float* fcW   = (const float*)d_in[14];
    const float* fcb   = (const float*)d_in[15];
    float* out = (float*)d_out;

    float* ws    = (float*)d_ws;
    float* h     = ws;                         // NN*128
    float* qkv   = h + (size_t)NN * 128;       // NN*384
    float* agg   = qkv + (size_t)NN * 384;     // NN*128
    float* Bf    = agg + (size_t)NN * 128;     // 128*384
    float* biasf = Bf + 128 * 384;             // 384
    int*   deg       = (int*)(biasf + 384);    // NN
    int*   offs      = deg + NN;               // NN
    int*   cursor    = offs + NN;              // NN
    int*   bsum      = cursor + NN;            // 256
    int*   boffs     = bsum + 256;             // 256
    int*   srcSorted = boffs + 256;            // NE

    // ---- CSR build (structure shared by both layers) ----
    hipMemsetAsync(deg, 0, (size_t)NN * sizeof(int), stream);
    hist_kernel<<<(NE + 255) / 256, 256, 0, stream>>>(eidx, deg);
    scan_blocks_kernel<<<NB_SCAN, 256, 0, stream>>>(deg, offs, bsum);
    scan_top_kernel<<<1, 256, 0, stream>>>(bsum, boffs);
    scan_add_kernel<<<NB_SCAN, 256, 0, stream>>>(offs, boffs, cursor);
    scatter_kernel<<<(NE + 255) / 256, 256, 0, stream>>>(eidx, cursor, srcSorted);

    for (int l = 0; l < 2; ++l) {
        const float* hc = (l == 0) ? x : h;
        fuse_kernel<<<194, 256, 0, stream>>>(
            Wq + l * 16384, bq + l * 128,
            Wk + l * 16384, bk + l * 128, a_rel + l * 2048,
            Wv + l * 16384, bv + l * 128, m_rel + l * 2048,
            p_rel + l * 8, Bf, biasf);
        gemm_kernel<0><<<dim3(625, 6), 256, 0, stream>>>(
            hc, Bf, biasf, qkv, nullptr, nullptr, 384);
        aggregate_kernel<<<NN / 4, 256, 0, stream>>>(
            qkv, deg, offs, srcSorted, agg);
        gemm_kernel<1><<<dim3(625, 2), 256, 0, stream>>>(
            agg, aW + l * 16384, ab + l * 128, h, hc, skip + l, 128);
    }
    gemm_kernel<2><<<dim3(625, 1), 256, 0, stream>>>(
        h, fcW, fcb, out, nullptr, nullptr, 64);
}

// Round 3
// 474.605 us; speedup vs baseline: 2.6096x; 1.1620x over previous
//
#include <hip/hip_runtime.h>
#include <hip/hip_bf16.h>
#include <math.h>

#define NN 40000
#define NE 640000
#define CDIM 128
#define HEADS 8
#define DHEAD 16
#define OUTDIM 64
#define NB_SCAN 157   // ceil(NN/256)

__device__ __forceinline__ float gelu_tanh(float x) {
    float x3 = x * x * x;
    float u = 0.7978845608028654f * (x + 0.044715f * x3);
    return 0.5f * x * (1.0f + tanhf(u));
}

__device__ __forceinline__ unsigned short f2bf(float v) {
    __hip_bfloat16 h = __float2bfloat16(v);
    return *reinterpret_cast<unsigned short*>(&h);
}

__device__ __forceinline__ float bf2f(unsigned short u) {
    union { unsigned int i; float f; } c;
    c.i = ((unsigned int)u) << 16;
    return c.f;
}

// Build fused QKV weight matrix Bf[128][384] and bias[384]:
//   cols   0..127 : Wq (copy), bias bq
//   cols 128..255 : Wk @ blockdiag(a_rel) scaled by p_rel[h]*0.25  (logit scale folded in)
//   cols 256..383 : Wv @ blockdiag(m_rel)
__global__ __launch_bounds__(256) void fuse_kernel(
    const float* __restrict__ Wq, const float* __restrict__ bq,
    const float* __restrict__ Wk, const float* __restrict__ bk,
    const float* __restrict__ a_rel,
    const float* __restrict__ Wv, const float* __restrict__ bv,
    const float* __restrict__ m_rel,
    const float* __restrict__ p_rel,
    float* __restrict__ Bf, float* __restrict__ biasf)
{
    int idx = blockIdx.x * 256 + threadIdx.x;
    if (idx >= 129 * 384) return;
    int r = idx / 384;          // 0..127 = weight row, 128 = bias row
    int col = idx - r * 384;
    float val;
    if (col < 128) {
        val = (r < 128) ? Wq[r * 128 + col] : bq[col];
    } else if (col < 256) {
        int cc = col - 128; int h = cc >> 4; int eo = cc & 15;
        float scale = p_rel[h] * 0.25f;   // p_rel * 1/sqrt(16)
        float s = 0.f;
        #pragma unroll
        for (int d = 0; d < 16; ++d) {
            float w = (r < 128) ? Wk[r * 128 + h * 16 + d] : bk[h * 16 + d];
            s += w * a_rel[h * 256 + d * 16 + eo];
        }
        val = s * scale;
    } else {
        int cc = col - 256; int h = cc >> 4; int eo = cc & 15;
        float s = 0.f;
        #pragma unroll
        for (int d = 0; d < 16; ++d) {
            float w = (r < 128) ? Wv[r * 128 + h * 16 + d] : bv[h * 16 + d];
            s += w * m_rel[h * 256 + d * 16 + eo];
        }
        val = s;
    }
    if (r < 128) Bf[r * 384 + col] = val;
    else         biasf[col] = val;
}

// Tiled f32 GEMM, tile 64x64, BK=64, A:[M x 128].
// MODE 0: QKV. cols 0..127 -> f32 q[NN][128]; cols 128..383 -> bf16 interleaved kvi[NN][256]
//         (lane layout: kvi[row*256 + p*4 + {k0,k1,v0,v1}] for channel pair p)
// MODE 1: gelu on A, epilogue h = relu(beta*(.) + (1-beta)*Hprev), write f32 Cout stride 128.
// MODE 2: plain f32 (final fc), stride Nld.
template <int MODE>
__global__ __launch_bounds__(256) void gemm_kernel(
    const float* __restrict__ A, const float* __restrict__ B,
    const float* __restrict__ bias, float* __restrict__ Cout,
    unsigned short* __restrict__ kvi,
    const float* __restrict__ Hprev, const float* __restrict__ skip_p,
    int Nld)
{
    __shared__ float As[64][68];
    __shared__ float Bs[64][64];
    int t = threadIdx.x;
    int row0 = blockIdx.x * 64;
    int col0 = blockIdx.y * 64;
    int ty = t >> 4, tx = t & 15;
    float acc[4][4] = {};

    for (int kb = 0; kb < 128; kb += 64) {
        #pragma unroll
        for (int i = 0; i < 4; ++i) {
            int idx = t + i * 256;
            int r = idx >> 4;
            int c4 = (idx & 15) << 2;
            float4 v = *(const float4*)(A + (size_t)(row0 + r) * 128 + kb + c4);
            if (MODE == 1) {
                v.x = gelu_tanh(v.x); v.y = gelu_tanh(v.y);
                v.z = gelu_tanh(v.z); v.w = gelu_tanh(v.w);
            }
            *(float4*)(&As[r][c4]) = v;
        }
        #pragma unroll
        for (int i = 0; i < 4; ++i) {
            int idx = t + i * 256;
            int r = idx >> 4;
            int c4 = (idx & 15) << 2;
            float4 v = *(const float4*)(B + (size_t)(kb + r) * Nld + col0 + c4);
            *(float4*)(&Bs[r][c4]) = v;
        }
        __syncthreads();
        #pragma unroll
        for (int k = 0; k < 64; k += 4) {
            float af[4][4], bf[4][4];
            *(float4*)&af[0][0] = *(const float4*)(&As[ty * 4 + 0][k]);
            *(float4*)&af[1][0] = *(const float4*)(&As[ty * 4 + 1][k]);
            *(float4*)&af[2][0] = *(const float4*)(&As[ty * 4 + 2][k]);
            *(float4*)&af[3][0] = *(const float4*)(&As[ty * 4 + 3][k]);
            *(float4*)&bf[0][0] = *(const float4*)(&Bs[k + 0][tx * 4]);
            *(float4*)&bf[1][0] = *(const float4*)(&Bs[k + 1][tx * 4]);
            *(float4*)&bf[2][0] = *(const float4*)(&Bs[k + 2][tx * 4]);
            *(float4*)&bf[3][0] = *(const float4*)(&Bs[k + 3][tx * 4]);
            #pragma unroll
            for (int kk = 0; kk < 4; ++kk)
                #pragma unroll
                for (int i = 0; i < 4; ++i)
                    #pragma unroll
                    for (int j = 0; j < 4; ++j)
                        acc[i][j] += af[i][kk] * bf[kk][j];
        }
        __syncthreads();
    }

    float beta = 0.f, omb = 0.f;
    if (MODE == 1) {
        float sv = skip_p[0];
        beta = 1.f / (1.f + expf(-sv));
        omb = 1.f - beta;
    }
    #pragma unroll
    for (int i = 0; i < 4; ++i) {
        int row = row0 + ty * 4 + i;
        int colb = col0 + tx * 4;
        float4 vv;
        vv.x = acc[i][0] + bias[colb + 0];
        vv.y = acc[i][1] + bias[colb + 1];
        vv.z = acc[i][2] + bias[colb + 2];
        vv.w = acc[i][3] + bias[colb + 3];
        if (MODE == 0) {
            if (col0 < 128) {
                *(float4*)(Cout + (size_t)row * 128 + colb) = vv;
            } else {
                int cc = colb - 128;           // 0..255, multiple of 4
                int half = cc >> 7;            // 0 = k2, 1 = v2
                int ch = cc & 127;             // channel within half
                size_t base = (size_t)row * 256 + (half << 1);
                ushort2 a01, a23;
                a01.x = f2bf(vv.x); a01.y = f2bf(vv.y);
                a23.x = f2bf(vv.z); a23.y = f2bf(vv.w);
                *(ushort2*)(kvi + base + (ch >> 1) * 4) = a01;
                *(ushort2*)(kvi + base + (ch >> 1) * 4 + 4) = a23;
            }
        } else if (MODE == 1) {
            float4 hp = *(const float4*)(Hprev + (size_t)row * 128 + colb);
            vv.x = fmaxf(beta * vv.x + omb * hp.x, 0.f);
            vv.y = fmaxf(beta * vv.y + omb * hp.y, 0.f);
            vv.z = fmaxf(beta * vv.z + omb * hp.z, 0.f);
            vv.w = fmaxf(beta * vv.w + omb * hp.w, 0.f);
            *(float4*)(Cout + (size_t)row * 128 + colb) = vv;
        } else {
            *(float4*)(Cout + (size_t)row * Nld + colb) = vv;
        }
    }
}

// ---------------- CSR build (once per call; both layers share structure) ---------

__global__ __launch_bounds__(256) void hist_kernel(
    const int* __restrict__ eidx, int* __restrict__ deg)
{
    int e = blockIdx.x * 256 + threadIdx.x;
    if (e < NE) atomicAdd(&deg[eidx[NE + e]], 1);
}

__global__ __launch_bounds__(256) void scan_blocks_kernel(
    const int* __restrict__ deg, int* __restrict__ offs, int* __restrict__ bsum)
{
    __shared__ int s[256];
    int t = threadIdx.x;
    int i = blockIdx.x * 256 + t;
    int v = (i < NN) ? deg[i] : 0;
    s[t] = v;
    __syncthreads();
    #pragma unroll
    for (int off = 1; off < 256; off <<= 1) {
        int u = (t >= off) ? s[t - off] : 0;
        __syncthreads();
        s[t] += u;
        __syncthreads();
    }
    if (i < NN) offs[i] = s[t] - v;      // exclusive within block
    if (t == 255) bsum[blockIdx.x] = s[255];
}

__global__ __launch_bounds__(256) void scan_top_kernel(
    const int* __restrict__ bsum, int* __restrict__ boffs)
{
    __shared__ int s[256];
    int t = threadIdx.x;
    int v = (t < NB_SCAN) ? bsum[t] : 0;
    s[t] = v;
    __syncthreads();
    #pragma unroll
    for (int off = 1; off < 256; off <<= 1) {
        int u = (t >= off) ? s[t - off] : 0;
        __syncthreads();
        s[t] += u;
        __syncthreads();
    }
    boffs[t] = s[t] - v;                 // exclusive
}

__global__ __launch_bounds__(256) void scan_add_kernel(
    int* __restrict__ offs, const int* __restrict__ boffs, int* __restrict__ cursor)
{
    int i = blockIdx.x * 256 + threadIdx.x;
    if (i < NN) {
        int o = offs[i] + boffs[blockIdx.x];
        offs[i] = o;
        cursor[i] = o;
    }
}

__global__ __launch_bounds__(256) void scatter_kernel(
    const int* __restrict__ eidx, int* __restrict__ cursor, int* __restrict__ srcSorted)
{
    int e = blockIdx.x * 256 + threadIdx.x;
    if (e < NE) {
        int s = eidx[e];
        int d = eidx[NE + e];
        int pos = atomicAdd(&cursor[d], 1);
        srcSorted[pos] = s;
    }
}

// ---------------- Fused per-destination softmax + aggregation --------------------
// One 64-lane wave per destination node; lane handles channels 2*lane, 2*lane+1.
// Head h = lane>>3 (8 lanes per head). Gather payload is bf16-interleaved:
// one ushort4 = [k_2l, k_2l+1, v_2l, v_2l+1] per lane per edge (8 B, dwordx2).
__global__ __launch_bounds__(256) void aggregate_kernel(
    const float* __restrict__ qf, const unsigned short* __restrict__ kvi,
    const int* __restrict__ deg, const int* __restrict__ offs,
    const int* __restrict__ srcSorted, float* __restrict__ agg)
{
    int wid = (blockIdx.x * 256 + threadIdx.x) >> 6;   // global wave id = node
    int lane = threadIdx.x & 63;
    int n = wid;
    float2 q2 = *(const float2*)(qf + (size_t)n * 128 + 2 * lane);
    int start = offs[n];
    int d = deg[n];
    float accx = 0.f, accy = 0.f, den = 0.f;

    int s_cur = (d > 0) ? srcSorted[start] : 0;
    int s_next = (d > 1) ? srcSorted[start + 1] : 0;
    ushort4 kv_cur = *(const ushort4*)(kvi + (size_t)s_cur * 256 + lane * 4);

    for (int j = 0; j < d; ++j) {
        int s_nn = (j + 2 < d) ? srcSorted[start + j + 2] : 0;
        ushort4 kv_next = *(const ushort4*)(kvi + (size_t)s_next * 256 + lane * 4);
        float kx = bf2f(kv_cur.x), ky = bf2f(kv_cur.y);
        float vx = bf2f(kv_cur.z), vy = bf2f(kv_cur.w);
        float p = q2.x * kx + q2.y * ky;
        p += __shfl_xor(p, 1, 8);
        p += __shfl_xor(p, 2, 8);
        p += __shfl_xor(p, 4, 8);
        float ev = expf(p);              // logits O(1): no max-subtraction needed
        den += ev;
        accx += vx * ev;
        accy += vy * ev;
        kv_cur = kv_next;
        s_next = s_nn;
    }
    float w = 1.0f / (den + 1e-16f);
    float2 o;
    o.x = accx * w;
    o.y = accy * w;
    *(float2*)(agg + (size_t)n * 128 + 2 * lane) = o;
}

extern "C" void kernel_launch(void* const* d_in, const int* in_sizes, int n_in,
                              void* d_out, int out_size, void* d_ws, size_t ws_size,
                              hipStream_t stream) {
    const float* x     = (const float*)d_in[0];
    const int*   eidx  = (const int*)d_in[1];
    const float* Wk    = (const float*)d_in[2];
    const float* bk    = (const float*)d_in[3];
    const float* Wq    = (const float*)d_in[4];
    const float* bq    = (const float*)d_in[5];
    const float* Wv    = (const float*)d_in[6];
    const float* bv    = (const float*)d_in[7];
    const float* a_rel = (const float*)d_in[8];
    const float* m_rel = (const float*)d_in[9];
    const float* p_rel = (const float*)d_in[10];
    const float* skip  = (const float*)d_in[11];
    const float* aW    = (const float*)d_in[12];
    const float* ab    = (const float*)d_in[13];
    const float* fcW   = (const float*)d_in[14];
    const float* fcb   = (const float*)d_in[15];
    float* out = (float*)d_out;

    float* ws    = (float*)d_ws;
    float* h     = ws;                          // NN*128
    float* qf    = h + (size_t)NN * 128;        // NN*128 (f32 q)
    float* agg   = qf + (size_t)NN * 128;       // NN*128
    float* Bf    = agg + (size_t)NN * 128;      // 128*384
    float* biasf = Bf + 128 * 384;              // 384
    unsigned short* kvi = (unsigned short*)(biasf + 384);  // NN*256 ushorts
    int*   deg       = (int*)(kvi + (size_t)NN * 256);     // NN
    int*   offs      = deg + NN;                // NN
    int*   cursor    = offs + NN;               // NN
    int*   bsum      = cursor + NN;             // 256
    int*   boffs     = bsum + 256;              // 256
    int*   srcSorted = boffs + 256;             // NE

    // ---- CSR build (structure shared by both layers) ----
    hipMemsetAsync(deg, 0, (size_t)NN * sizeof(int), stream);
    hist_kernel<<<(NE + 255) / 256, 256, 0, stream>>>(eidx, deg);
    scan_blocks_kernel<<<NB_SCAN, 256, 0, stream>>>(deg, offs, bsum);
    scan_top_kernel<<<1, 256, 0, stream>>>(bsum, boffs);
    scan_add_kernel<<<NB_SCAN, 256, 0, stream>>>(offs, boffs, cursor);
    scatter_kernel<<<(NE + 255) / 256, 256, 0, stream>>>(eidx, cursor, srcSorted);

    for (int l = 0; l < 2; ++l) {
        const float* hc = (l == 0) ? x : h;
        fuse_kernel<<<194, 256, 0, stream>>>(
            Wq + l * 16384, bq + l * 128,
            Wk + l * 16384, bk + l * 128, a_rel + l * 2048,
            Wv + l * 16384, bv + l * 128, m_rel + l * 2048,
            p_rel + l * 8, Bf, biasf);
        gemm_kernel<0><<<dim3(625, 6), 256, 0, stream>>>(
            hc, Bf, biasf, qf, kvi, nullptr, nullptr, 384);
        aggregate_kernel<<<NN / 4, 256, 0, stream>>>(
            qf, kvi, deg, offs, srcSorted, agg);
        gemm_kernel<1><<<dim3(625, 2), 256, 0, stream>>>(
            agg, aW + l * 16384, ab + l * 128, h, nullptr, hc, skip + l, 128);
    }
    gemm_kernel<2><<<dim3(625, 1), 256, 0, stream>>>(
        h, fcW, fcb, out, nullptr, nullptr, nullptr, 64);
}

// Round 4
// 373.646 us; speedup vs baseline: 3.3147x; 1.2702x over previous
//
#include <hip/hip_runtime.h>
#include <hip/hip_bf16.h>
#include <math.h>

#define NN 40000
#define NE 640000
#define CDIM 128
#define HEADS 8
#define DHEAD 16
#define OUTDIM 64
#define NB_SCAN 157   // ceil(NN/256)

typedef __attribute__((ext_vector_type(8))) short short8;
typedef __attribute__((ext_vector_type(4))) float f32x4;

__device__ __forceinline__ float gelu_tanh(float x) {
    float x3 = x * x * x;
    float u = 0.7978845608028654f * (x + 0.044715f * x3);
    return 0.5f * x * (1.0f + tanhf(u));
}

__device__ __forceinline__ unsigned short f2bf(float v) {
    __hip_bfloat16 h = __float2bfloat16(v);
    return *reinterpret_cast<unsigned short*>(&h);
}

__device__ __forceinline__ float bf2f(unsigned short u) {
    union { unsigned int i; float f; } c;
    c.i = ((unsigned int)u) << 16;
    return c.f;
}

// Build fused QKV weight, TRANSPOSED bf16: BfT[384][128], bias f32[384].
//   cols   0..127 : Wq (copy), bias bq
//   cols 128..255 : Wk @ blockdiag(a_rel) scaled by p_rel[h]*0.25
//   cols 256..383 : Wv @ blockdiag(m_rel)
__global__ __launch_bounds__(256) void fuse_kernel(
    const float* __restrict__ Wq, const float* __restrict__ bq,
    const float* __restrict__ Wk, const float* __restrict__ bk,
    const float* __restrict__ a_rel,
    const float* __restrict__ Wv, const float* __restrict__ bv,
    const float* __restrict__ m_rel,
    const float* __restrict__ p_rel,
    unsigned short* __restrict__ BfT, float* __restrict__ biasf)
{
    int idx = blockIdx.x * 256 + threadIdx.x;
    if (idx >= 129 * 384) return;
    int r = idx / 384;          // 0..127 = weight row (k), 128 = bias row
    int col = idx - r * 384;
    float val;
    if (col < 128) {
        val = (r < 128) ? Wq[r * 128 + col] : bq[col];
    } else if (col < 256) {
        int cc = col - 128; int h = cc >> 4; int eo = cc & 15;
        float scale = p_rel[h] * 0.25f;   // p_rel * 1/sqrt(16)
        float s = 0.f;
        #pragma unroll
        for (int d = 0; d < 16; ++d) {
            float w = (r < 128) ? Wk[r * 128 + h * 16 + d] : bk[h * 16 + d];
            s += w * a_rel[h * 256 + d * 16 + eo];
        }
        val = s * scale;
    } else {
        int cc = col - 256; int h = cc >> 4; int eo = cc & 15;
        float s = 0.f;
        #pragma unroll
        for (int d = 0; d < 16; ++d) {
            float w = (r < 128) ? Wv[r * 128 + h * 16 + d] : bv[h * 16 + d];
            s += w * m_rel[h * 256 + d * 16 + eo];
        }
        val = s;
    }
    if (r < 128) BfT[(size_t)col * 128 + r] = f2bf(val);
    else         biasf[col] = val;
}

// Transpose+convert 128x128 f32 W -> bf16 WT[128][128] (WT[c][r] = W[r][c])
__global__ __launch_bounds__(256) void convT_kernel(
    const float* __restrict__ W, unsigned short* __restrict__ WT)
{
    int idx = blockIdx.x * 256 + threadIdx.x;   // 16384 total
    int r = idx >> 7, c = idx & 127;
    WT[(size_t)c * 128 + r] = f2bf(W[(size_t)r * 128 + c]);
}

// ---------------- MFMA bf16 GEMM: C[64 rows x Ncols] per block -------------------
// A: [M x 128] f32 (converted to bf16 in staging, gelu if MODE 1)
// BT: [Ncols x 128] bf16 (transposed weight)
// MODE 0 (QKV): cols 0..127 -> f32 q; cols 128..383 -> bf16 interleaved kvi
// MODE 1 (agg): epilogue h = relu(beta*(acc+bias) + (1-beta)*Hprev), f32 out
template <int MODE>
__global__ __launch_bounds__(256) void mfma_gemm_kernel(
    const float* __restrict__ A, const unsigned short* __restrict__ BT,
    const float* __restrict__ bias, float* __restrict__ Cout,
    unsigned short* __restrict__ kvi, const float* __restrict__ Hprev,
    const float* __restrict__ skip_p, int Ncols)
{
    __shared__ unsigned short As[64][136];   // +8 pad: banks shift 4/row
    __shared__ unsigned short Bs[64][136];
    int t = threadIdx.x;
    int row0 = blockIdx.x * 64;
    int w = t >> 6;           // wave 0..3 -> rows 16w..16w+15
    int l = t & 63;
    int lr = l & 15;
    int quad = l >> 4;

    // stage A tile (64 x 128) as bf16
    #pragma unroll
    for (int i = 0; i < 4; ++i) {
        int idx = t + i * 256;
        int r = idx >> 4;
        int c8 = (idx & 15) * 8;
        float4 a0 = *(const float4*)(A + (size_t)(row0 + r) * 128 + c8);
        float4 a1 = *(const float4*)(A + (size_t)(row0 + r) * 128 + c8 + 4);
        if (MODE == 1) {
            a0.x = gelu_tanh(a0.x); a0.y = gelu_tanh(a0.y);
            a0.z = gelu_tanh(a0.z); a0.w = gelu_tanh(a0.w);
            a1.x = gelu_tanh(a1.x); a1.y = gelu_tanh(a1.y);
            a1.z = gelu_tanh(a1.z); a1.w = gelu_tanh(a1.w);
        }
        ushort4 u0, u1;
        u0.x = f2bf(a0.x); u0.y = f2bf(a0.y); u0.z = f2bf(a0.z); u0.w = f2bf(a0.w);
        u1.x = f2bf(a1.x); u1.y = f2bf(a1.y); u1.z = f2bf(a1.z); u1.w = f2bf(a1.w);
        *(ushort4*)(&As[r][c8]) = u0;
        *(ushort4*)(&As[r][c8 + 4]) = u1;
    }

    float beta = 0.f, omb = 0.f;
    if (MODE == 1) {
        float sv = skip_p[0];
        beta = 1.f / (1.f + expf(-sv));
        omb = 1.f - beta;
    }

    int nct = Ncols >> 6;
    for (int ct = 0; ct < nct; ++ct) {
        __syncthreads();   // previous iter's Bs reads done (also orders As stage)
        #pragma unroll
        for (int i = 0; i < 4; ++i) {
            int idx = t + i * 256;
            int r = idx >> 4;
            int c8 = (idx & 15) * 8;
            ushort4 b0 = *(const ushort4*)(BT + (size_t)(ct * 64 + r) * 128 + c8);
            ushort4 b1 = *(const ushort4*)(BT + (size_t)(ct * 64 + r) * 128 + c8 + 4);
            *(ushort4*)(&Bs[r][c8]) = b0;
            *(ushort4*)(&Bs[r][c8 + 4]) = b1;
        }
        __syncthreads();

        f32x4 acc[4] = {{0.f,0.f,0.f,0.f},{0.f,0.f,0.f,0.f},
                        {0.f,0.f,0.f,0.f},{0.f,0.f,0.f,0.f}};
        #pragma unroll
        for (int kc = 0; kc < 4; ++kc) {
            short8 af = *(const short8*)(&As[w * 16 + lr][kc * 32 + quad * 8]);
            #pragma unroll
            for (int n4 = 0; n4 < 4; ++n4) {
                short8 bfr = *(const short8*)(&Bs[n4 * 16 + lr][kc * 32 + quad * 8]);
                acc[n4] = __builtin_amdgcn_mfma_f32_16x16x32_bf16(af, bfr, acc[n4], 0, 0, 0);
            }
        }

        #pragma unroll
        for (int n4 = 0; n4 < 4; ++n4) {
            int col = ct * 64 + n4 * 16 + lr;
            float bv = bias[col];
            #pragma unroll
            for (int rr = 0; rr < 4; ++rr) {
                int row = row0 + w * 16 + quad * 4 + rr;
                float v = acc[n4][rr] + bv;
                if (MODE == 0) {
                    if (col < 128) {
                        Cout[(size_t)row * 128 + col] = v;
                    } else {
                        int cc = col - 128;
                        int half = cc >> 7;
                        int ch = cc & 127;
                        kvi[(size_t)row * 256 + (ch >> 1) * 4 + half * 2 + (ch & 1)] = f2bf(v);
                    }
                } else {
                    float hp = Hprev[(size_t)row * 128 + col];
                    v = fmaxf(beta * v + omb * hp, 0.f);
                    Cout[(size_t)row * 128 + col] = v;
                }
            }
        }
    }
}

// ---------------- f32 GEMM for final fc (N=64): accuracy-preserving --------------
__global__ __launch_bounds__(256) void fc_kernel(
    const float* __restrict__ A, const float* __restrict__ B,
    const float* __restrict__ bias, float* __restrict__ Cout)
{
    __shared__ float As[64][68];
    __shared__ float Bs[64][64];
    int t = threadIdx.x;
    int row0 = blockIdx.x * 64;
    int ty = t >> 4, tx = t & 15;
    float acc[4][4] = {};

    for (int kb = 0; kb < 128; kb += 64) {
        #pragma unroll
        for (int i = 0; i < 4; ++i) {
            int idx = t + i * 256;
            int r = idx >> 4;
            int c4 = (idx & 15) << 2;
            float4 v = *(const float4*)(A + (size_t)(row0 + r) * 128 + kb + c4);
            *(float4*)(&As[r][c4]) = v;
        }
        #pragma unroll
        for (int i = 0; i < 4; ++i) {
            int idx = t + i * 256;
            int r = idx >> 4;
            int c4 = (idx & 15) << 2;
            float4 v = *(const float4*)(B + (size_t)(kb + r) * 64 + c4);
            *(float4*)(&Bs[r][c4]) = v;
        }
        __syncthreads();
        #pragma unroll
        for (int k = 0; k < 64; k += 4) {
            float af[4][4], bf[4][4];
            *(float4*)&af[0][0] = *(const float4*)(&As[ty * 4 + 0][k]);
            *(float4*)&af[1][0] = *(const float4*)(&As[ty * 4 + 1][k]);
            *(float4*)&af[2][0] = *(const float4*)(&As[ty * 4 + 2][k]);
            *(float4*)&af[3][0] = *(const float4*)(&As[ty * 4 + 3][k]);
            *(float4*)&bf[0][0] = *(const float4*)(&Bs[k + 0][tx * 4]);
            *(float4*)&bf[1][0] = *(const float4*)(&Bs[k + 1][tx * 4]);
            *(float4*)&bf[2][0] = *(const float4*)(&Bs[k + 2][tx * 4]);
            *(float4*)&bf[3][0] = *(const float4*)(&Bs[k + 3][tx * 4]);
            #pragma unroll
            for (int kk = 0; kk < 4; ++kk)
                #pragma unroll
                for (int i = 0; i < 4; ++i)
                    #pragma unroll
                    for (int j = 0; j < 4; ++j)
                        acc[i][j] += af[i][kk] * bf[kk][j];
        }
        __syncthreads();
    }
    #pragma unroll
    for (int i = 0; i < 4; ++i) {
        int row = row0 + ty * 4 + i;
        int colb = tx * 4;
        float4 vv;
        vv.x = acc[i][0] + bias[colb + 0];
        vv.y = acc[i][1] + bias[colb + 1];
        vv.z = acc[i][2] + bias[colb + 2];
        vv.w = acc[i][3] + bias[colb + 3];
        *(float4*)(Cout + (size_t)row * 64 + colb) = vv;
    }
}

// ---------------- CSR build (once per call; both layers share structure) ---------

__global__ __launch_bounds__(256) void hist_kernel(
    const int* __restrict__ eidx, int* __restrict__ deg)
{
    int e = blockIdx.x * 256 + threadIdx.x;
    if (e < NE) atomicAdd(&deg[eidx[NE + e]], 1);
}

__global__ __launch_bounds__(256) void scan_blocks_kernel(
    const int* __restrict__ deg, int* __restrict__ offs, int* __restrict__ bsum)
{
    __shared__ int s[256];
    int t = threadIdx.x;
    int i = blockIdx.x * 256 + t;
    int v = (i < NN) ? deg[i] : 0;
    s[t] = v;
    __syncthreads();
    #pragma unroll
    for (int off = 1; off < 256; off <<= 1) {
        int u = (t >= off) ? s[t - off] : 0;
        __syncthreads();
        s[t] += u;
        __syncthreads();
    }
    if (i < NN) offs[i] = s[t] - v;
    if (t == 255) bsum[blockIdx.x] = s[255];
}

__global__ __launch_bounds__(256) void scan_top_kernel(
    const int* __restrict__ bsum, int* __restrict__ boffs)
{
    __shared__ int s[256];
    int t = threadIdx.x;
    int v = (t < NB_SCAN) ? bsum[t] : 0;
    s[t] = v;
    __syncthreads();
    #pragma unroll
    for (int off = 1; off < 256; off <<= 1) {
        int u = (t >= off) ? s[t - off] : 0;
        __syncthreads();
        s[t] += u;
        __syncthreads();
    }
    boffs[t] = s[t] - v;
}

__global__ __launch_bounds__(256) void scan_add_kernel(
    int* __restrict__ offs, const int* __restrict__ boffs, int* __restrict__ cursor)
{
    int i = blockIdx.x * 256 + threadIdx.x;
    if (i < NN) {
        int o = offs[i] + boffs[blockIdx.x];
        offs[i] = o;
        cursor[i] = o;
    }
}

__global__ __launch_bounds__(256) void scatter_kernel(
    const int* __restrict__ eidx, int* __restrict__ cursor, int* __restrict__ srcSorted)
{
    int e = blockIdx.x * 256 + threadIdx.x;
    if (e < NE) {
        int s = eidx[e];
        int d = eidx[NE + e];
        int pos = atomicAdd(&cursor[d], 1);
        srcSorted[pos] = s;
    }
}

// ---------------- Fused per-destination softmax + aggregation --------------------
__global__ __launch_bounds__(256) void aggregate_kernel(
    const float* __restrict__ qf, const unsigned short* __restrict__ kvi,
    const int* __restrict__ deg, const int* __restrict__ offs,
    const int* __restrict__ srcSorted, float* __restrict__ agg)
{
    int wid = (blockIdx.x * 256 + threadIdx.x) >> 6;
    int lane = threadIdx.x & 63;
    int n = wid;
    float2 q2 = *(const float2*)(qf + (size_t)n * 128 + 2 * lane);
    int start = offs[n];
    int d = deg[n];
    float accx = 0.f, accy = 0.f, den = 0.f;

    int s_cur = (d > 0) ? srcSorted[start] : 0;
    int s_next = (d > 1) ? srcSorted[start + 1] : 0;
    ushort4 kv_cur = *(const ushort4*)(kvi + (size_t)s_cur * 256 + lane * 4);

    for (int j = 0; j < d; ++j) {
        int s_nn = (j + 2 < d) ? srcSorted[start + j + 2] : 0;
        ushort4 kv_next = *(const ushort4*)(kvi + (size_t)s_next * 256 + lane * 4);
        float kx = bf2f(kv_cur.x), ky = bf2f(kv_cur.y);
        float vx = bf2f(kv_cur.z), vy = bf2f(kv_cur.w);
        float p = q2.x * kx + q2.y * ky;
        p += __shfl_xor(p, 1, 8);
        p += __shfl_xor(p, 2, 8);
        p += __shfl_xor(p, 4, 8);
        float ev = expf(p);
        den += ev;
        accx += vx * ev;
        accy += vy * ev;
        kv_cur = kv_next;
        s_next = s_nn;
    }
    float w = 1.0f / (den + 1e-16f);
    float2 o;
    o.x = accx * w;
    o.y = accy * w;
    *(float2*)(agg + (size_t)n * 128 + 2 * lane) = o;
}

extern "C" void kernel_launch(void* const* d_in, const int* in_sizes, int n_in,
                              void* d_out, int out_size, void* d_ws, size_t ws_size,
                              hipStream_t stream) {
    const float* x     = (const float*)d_in[0];
    const int*   eidx  = (const int*)d_in[1];
    const float* Wk    = (const float*)d_in[2];
    const float* bk    = (const float*)d_in[3];
    const float* Wq    = (const float*)d_in[4];
    const float* bq    = (const float*)d_in[5];
    const float* Wv    = (const float*)d_in[6];
    const float* bv    = (const float*)d_in[7];
    const float* a_rel = (const float*)d_in[8];
    const float* m_rel = (const float*)d_in[9];
    const float* p_rel = (const float*)d_in[10];
    const float* skip  = (const float*)d_in[11];
    const float* aW    = (const float*)d_in[12];
    const float* ab    = (const float*)d_in[13];
    const float* fcW   = (const float*)d_in[14];
    const float* fcb   = (const float*)d_in[15];
    float* out = (float*)d_out;

    float* ws    = (float*)d_ws;
    float* h     = ws;                          // NN*128
    float* qf    = h + (size_t)NN * 128;        // NN*128
    float* agg   = qf + (size_t)NN * 128;       // NN*128
    float* biasf = agg + (size_t)NN * 128;      // 384
    unsigned short* BfT = (unsigned short*)(biasf + 384);   // 384*128
    unsigned short* aWT = BfT + 384 * 128;                  // 128*128
    unsigned short* kvi = aWT + 128 * 128;                  // NN*256
    int*   deg       = (int*)(kvi + (size_t)NN * 256);      // NN
    int*   offs      = deg + NN;
    int*   cursor    = offs + NN;
    int*   bsum      = cursor + NN;             // 256
    int*   boffs     = bsum + 256;              // 256
    int*   srcSorted = boffs + 256;             // NE

    // ---- CSR build (structure shared by both layers) ----
    hipMemsetAsync(deg, 0, (size_t)NN * sizeof(int), stream);
    hist_kernel<<<(NE + 255) / 256, 256, 0, stream>>>(eidx, deg);
    scan_blocks_kernel<<<NB_SCAN, 256, 0, stream>>>(deg, offs, bsum);
    scan_top_kernel<<<1, 256, 0, stream>>>(bsum, boffs);
    scan_add_kernel<<<NB_SCAN, 256, 0, stream>>>(offs, boffs, cursor);
    scatter_kernel<<<(NE + 255) / 256, 256, 0, stream>>>(eidx, cursor, srcSorted);

    for (int l = 0; l < 2; ++l) {
        const float* hc = (l == 0) ? x : h;
        fuse_kernel<<<194, 256, 0, stream>>>(
            Wq + l * 16384, bq + l * 128,
            Wk + l * 16384, bk + l * 128, a_rel + l * 2048,
            Wv + l * 16384, bv + l * 128, m_rel + l * 2048,
            p_rel + l * 8, BfT, biasf);
        convT_kernel<<<64, 256, 0, stream>>>(aW + l * 16384, aWT);
        mfma_gemm_kernel<0><<<625, 256, 0, stream>>>(
            hc, BfT, biasf, qf, kvi, nullptr, nullptr, 384);
        aggregate_kernel<<<NN / 4, 256, 0, stream>>>(
            qf, kvi, deg, offs, srcSorted, agg);
        mfma_gemm_kernel<1><<<625, 256, 0, stream>>>(
            agg, aWT, ab + l * 128, h, nullptr, hc, skip + l, 128);
    }
    fc_kernel<<<625, 256, 0, stream>>>(h, fcW, fcb, out);
}